// Round 2
// baseline (559.534 us; speedup 1.0000x reference)
//
#include <hip/hip_runtime.h>
#include <hip/hip_bf16.h>
#include <stdint.h>

// FeatureVolume: trilinear grid_sample of fm [32,129,129,129] at 1M points.
// Strategy: transpose fm -> [DHW, 32] bf16 in d_ws (L3-resident, channels
// contiguous), then gather 8 corners/point with uint2 (4 bf16 ch/lane).

#define GRIDW 129
#define S_TOTAL (129 * 129 * 129)  // 2146689
#define NCH 32

static __device__ __forceinline__ ushort f32_to_bf16_rne(float f) {
    uint32_t u = __float_as_uint(f);
    u += 0x7FFFu + ((u >> 16) & 1u);
    return (ushort)(u >> 16);
}

// fm [32][S] f32  ->  vol [S][32] bf16
// Block = 256 threads handles a tile of 256 s-values x 32 channels.
// Phase 1: coalesced f32 reads (lane-consecutive s), LDS store pad 33 (2-way max).
// Phase 2: each lane packs 8 bf16 -> one 16B store, wave stores 1KB contiguous.
__global__ __launch_bounds__(256) void fv_transpose(const float* __restrict__ fm,
                                                    ushort* __restrict__ vol) {
    __shared__ float tile[256 * 33];
    const int tid = threadIdx.x;
    const int s = blockIdx.x * 256 + tid;
    const bool valid = (s < S_TOTAL);
#pragma unroll
    for (int c = 0; c < NCH; ++c) {
        float v = valid ? fm[(size_t)c * S_TOTAL + s] : 0.0f;
        tile[tid * 33 + c] = v;  // bank = (tid + c) % 32 -> 2-way (free)
    }
    __syncthreads();
    const int sl = tid >> 2;         // 0..63
    const int c0 = (tid & 3) * 8;    // 0,8,16,24
#pragma unroll
    for (int k = 0; k < 4; ++k) {
        const int srow = k * 64 + sl;
        const int sg = blockIdx.x * 256 + srow;
        if (sg < S_TOTAL) {
            uint32_t w[4];
#pragma unroll
            for (int j = 0; j < 4; ++j) {
                const ushort lo = f32_to_bf16_rne(tile[srow * 33 + c0 + 2 * j]);
                const ushort hi = f32_to_bf16_rne(tile[srow * 33 + c0 + 2 * j + 1]);
                w[j] = (uint32_t)lo | ((uint32_t)hi << 16);
            }
            *reinterpret_cast<uint4*>(vol + (size_t)sg * NCH + c0) =
                make_uint4(w[0], w[1], w[2], w[3]);
        }
    }
}

static __device__ __forceinline__ void bf16x4_to_f(uint2 q, float f[4]) {
    f[0] = __uint_as_float(q.x << 16);
    f[1] = __uint_as_float(q.x & 0xFFFF0000u);
    f[2] = __uint_as_float(q.y << 16);
    f[3] = __uint_as_float(q.y & 0xFFFF0000u);
}

// 8 lanes per point, 4 channels per lane. Corner gather = one 64B segment.
__global__ __launch_bounds__(256) void fv_sample(const float* __restrict__ x,
                                                 const ushort* __restrict__ vol,
                                                 float* __restrict__ out,
                                                 int npts) {
    const int gid = blockIdx.x * 256 + threadIdx.x;
    const int p = gid >> 3;
    if (p >= npts) return;
    const int c0 = (gid & 7) * 4;

    const float cx = x[3 * p + 0];
    const float cy = x[3 * p + 1];
    const float cz = x[3 * p + 2];

    // match ref: clip((c+1)*0.5*(size-1), 0, size-1)
    const float fx = fminf(fmaxf((cx + 1.0f) * 0.5f * 128.0f, 0.0f), 128.0f);
    const float fy = fminf(fmaxf((cy + 1.0f) * 0.5f * 128.0f, 0.0f), 128.0f);
    const float fz = fminf(fmaxf((cz + 1.0f) * 0.5f * 128.0f, 0.0f), 128.0f);

    const float fx0 = floorf(fx), fy0 = floorf(fy), fz0 = floorf(fz);
    const int ix0 = (int)fx0, iy0 = (int)fy0, iz0 = (int)fz0;
    const float tx = fx - fx0, ty = fy - fy0, tz = fz - fz0;
    const int dX = (ix0 < GRIDW - 1) ? 1 : 0;
    const int dY = (iy0 < GRIDW - 1) ? GRIDW : 0;
    const int dZ = (iz0 < GRIDW - 1) ? (GRIDW * GRIDW) : 0;

    const int s000 = (iz0 * GRIDW + iy0) * GRIDW + ix0;
    const int s001 = s000 + dX;
    const int s010 = s000 + dY;
    const int s011 = s010 + dX;
    const int s100 = s000 + dZ;
    const int s101 = s100 + dX;
    const int s110 = s100 + dY;
    const int s111 = s110 + dX;

    const ushort* b = vol + c0;
    const uint2 q000 = *reinterpret_cast<const uint2*>(b + (size_t)s000 * NCH);
    const uint2 q001 = *reinterpret_cast<const uint2*>(b + (size_t)s001 * NCH);
    const uint2 q010 = *reinterpret_cast<const uint2*>(b + (size_t)s010 * NCH);
    const uint2 q011 = *reinterpret_cast<const uint2*>(b + (size_t)s011 * NCH);
    const uint2 q100 = *reinterpret_cast<const uint2*>(b + (size_t)s100 * NCH);
    const uint2 q101 = *reinterpret_cast<const uint2*>(b + (size_t)s101 * NCH);
    const uint2 q110 = *reinterpret_cast<const uint2*>(b + (size_t)s110 * NCH);
    const uint2 q111 = *reinterpret_cast<const uint2*>(b + (size_t)s111 * NCH);

    const float wx1 = tx, wx0 = 1.0f - tx;
    const float wy1 = ty, wy0 = 1.0f - ty;
    const float wz1 = tz, wz0 = 1.0f - tz;
    const float w000 = wz0 * wy0 * wx0, w001 = wz0 * wy0 * wx1;
    const float w010 = wz0 * wy1 * wx0, w011 = wz0 * wy1 * wx1;
    const float w100 = wz1 * wy0 * wx0, w101 = wz1 * wy0 * wx1;
    const float w110 = wz1 * wy1 * wx0, w111 = wz1 * wy1 * wx1;

    float f[4], acc[4];
    bf16x4_to_f(q000, f);
#pragma unroll
    for (int j = 0; j < 4; ++j) acc[j] = w000 * f[j];
    bf16x4_to_f(q001, f);
#pragma unroll
    for (int j = 0; j < 4; ++j) acc[j] += w001 * f[j];
    bf16x4_to_f(q010, f);
#pragma unroll
    for (int j = 0; j < 4; ++j) acc[j] += w010 * f[j];
    bf16x4_to_f(q011, f);
#pragma unroll
    for (int j = 0; j < 4; ++j) acc[j] += w011 * f[j];
    bf16x4_to_f(q100, f);
#pragma unroll
    for (int j = 0; j < 4; ++j) acc[j] += w100 * f[j];
    bf16x4_to_f(q101, f);
#pragma unroll
    for (int j = 0; j < 4; ++j) acc[j] += w101 * f[j];
    bf16x4_to_f(q110, f);
#pragma unroll
    for (int j = 0; j < 4; ++j) acc[j] += w110 * f[j];
    bf16x4_to_f(q111, f);
#pragma unroll
    for (int j = 0; j < 4; ++j) acc[j] += w111 * f[j];

    *reinterpret_cast<float4*>(out + (size_t)p * NCH + c0) =
        make_float4(acc[0], acc[1], acc[2], acc[3]);
}

// Fallback (ws too small for bf16 volume): gather directly from fm [C][S] f32.
__global__ __launch_bounds__(256) void fv_sample_direct(const float* __restrict__ x,
                                                        const float* __restrict__ fm,
                                                        float* __restrict__ out,
                                                        int npts) {
    const int gid = blockIdx.x * 256 + threadIdx.x;
    const int p = gid >> 5;
    if (p >= npts) return;
    const int c = gid & 31;

    const float cx = x[3 * p + 0];
    const float cy = x[3 * p + 1];
    const float cz = x[3 * p + 2];

    const float fx = fminf(fmaxf((cx + 1.0f) * 0.5f * 128.0f, 0.0f), 128.0f);
    const float fy = fminf(fmaxf((cy + 1.0f) * 0.5f * 128.0f, 0.0f), 128.0f);
    const float fz = fminf(fmaxf((cz + 1.0f) * 0.5f * 128.0f, 0.0f), 128.0f);

    const float fx0 = floorf(fx), fy0 = floorf(fy), fz0 = floorf(fz);
    const int ix0 = (int)fx0, iy0 = (int)fy0, iz0 = (int)fz0;
    const float tx = fx - fx0, ty = fy - fy0, tz = fz - fz0;
    const int dX = (ix0 < GRIDW - 1) ? 1 : 0;
    const int dY = (iy0 < GRIDW - 1) ? GRIDW : 0;
    const int dZ = (iz0 < GRIDW - 1) ? (GRIDW * GRIDW) : 0;

    const int s000 = (iz0 * GRIDW + iy0) * GRIDW + ix0;
    const float* b = fm + (size_t)c * S_TOTAL;
    const float v000 = b[s000];
    const float v001 = b[s000 + dX];
    const float v010 = b[s000 + dY];
    const float v011 = b[s000 + dY + dX];
    const float v100 = b[s000 + dZ];
    const float v101 = b[s000 + dZ + dX];
    const float v110 = b[s000 + dZ + dY];
    const float v111 = b[s000 + dZ + dY + dX];

    const float wx1 = tx, wx0 = 1.0f - tx;
    const float wy1 = ty, wy0 = 1.0f - ty;
    const float wz1 = tz, wz0 = 1.0f - tz;

    const float r = v000 * (wz0 * wy0 * wx0) + v001 * (wz0 * wy0 * wx1) +
                    v010 * (wz0 * wy1 * wx0) + v011 * (wz0 * wy1 * wx1) +
                    v100 * (wz1 * wy0 * wx0) + v101 * (wz1 * wy0 * wx1) +
                    v110 * (wz1 * wy1 * wx0) + v111 * (wz1 * wy1 * wx1);

    out[(size_t)p * NCH + c] = r;
}

extern "C" void kernel_launch(void* const* d_in, const int* in_sizes, int n_in,
                              void* d_out, int out_size, void* d_ws, size_t ws_size,
                              hipStream_t stream) {
    const float* x = (const float*)d_in[0];
    const float* fm = (const float*)d_in[1];
    float* out = (float*)d_out;
    const int npts = in_sizes[0] / 3;

    const size_t need = (size_t)S_TOTAL * NCH * sizeof(ushort);  // ~137.4 MB
    if (ws_size >= need) {
        const int tb = (S_TOTAL + 255) / 256;  // 8386
        fv_transpose<<<tb, 256, 0, stream>>>(fm, (ushort*)d_ws);
        const int nthreads = npts * 8;  // 8 lanes per point
        fv_sample<<<(nthreads + 255) / 256, 256, 0, stream>>>(
            x, (const ushort*)d_ws, out, npts);
    } else {
        const int nthreads = npts * 32;
        fv_sample_direct<<<(nthreads + 255) / 256, 256, 0, stream>>>(x, fm, out, npts);
    }
}

// Round 7
// 523.061 us; speedup vs baseline: 1.0697x; 1.0697x over previous
//
#include <hip/hip_runtime.h>
#include <hip/hip_bf16.h>
#include <stdint.h>

// FeatureVolume: trilinear grid_sample of fm [32,129,129,129] at 1M points.
// Strategy: transpose fm -> [DHW, 32] bf16 in d_ws (L3-resident, channels
// contiguous), then gather 8 corners/point with uint2 (4 bf16 ch/lane).
// Round 4: nontemporal fm loads + nontemporal out stores via native vector
// type (fix round-3 compile error), branchless clamped transpose loads,
// factored weight math, u32 element offsets.

#define GRIDW 129
#define S_TOTAL (129 * 129 * 129)  // 2146689
#define NCH 32

typedef float f32x4 __attribute__((ext_vector_type(4)));

static __device__ __forceinline__ ushort f32_to_bf16_rne(float f) {
    uint32_t u = __float_as_uint(f);
    u += 0x7FFFu + ((u >> 16) & 1u);
    return (ushort)(u >> 16);
}

// fm [32][S] f32  ->  vol [S][32] bf16
// Block = 256 threads handles a tile of 256 s-values x 32 channels.
// Phase 1: coalesced f32 reads (lane-consecutive s), LDS store pad 33 (2-way max).
// Phase 2: each lane packs 8 bf16 -> one 16B store, wave stores 1KB contiguous.
__global__ __launch_bounds__(256) void fv_transpose(const float* __restrict__ fm,
                                                    ushort* __restrict__ vol) {
    __shared__ float tile[256 * 33];
    const int tid = threadIdx.x;
    const int s0 = blockIdx.x * 256;
    // clamp instead of predicate: unconditional loads, garbage rows masked at store
    const int s = min(s0 + tid, S_TOTAL - 1);
    const float* p = fm + s;
#pragma unroll
    for (int c = 0; c < NCH; ++c) {
        tile[tid * 33 + c] = __builtin_nontemporal_load(p);  // fm is read-once
        p += S_TOTAL;
    }
    __syncthreads();
    const int sl = tid >> 2;         // 0..63
    const int c0 = (tid & 3) * 8;    // 0,8,16,24
#pragma unroll
    for (int k = 0; k < 4; ++k) {
        const int srow = k * 64 + sl;
        const int sg = s0 + srow;
        if (sg < S_TOTAL) {
            uint32_t w[4];
#pragma unroll
            for (int j = 0; j < 4; ++j) {
                const ushort lo = f32_to_bf16_rne(tile[srow * 33 + c0 + 2 * j]);
                const ushort hi = f32_to_bf16_rne(tile[srow * 33 + c0 + 2 * j + 1]);
                w[j] = (uint32_t)lo | ((uint32_t)hi << 16);
            }
            // cached store: we WANT vol resident in L2/L3 for the sample pass
            *reinterpret_cast<uint4*>(vol + (size_t)sg * NCH + c0) =
                make_uint4(w[0], w[1], w[2], w[3]);
        }
    }
}

static __device__ __forceinline__ void bf16x4_to_f(uint2 q, float f[4]) {
    f[0] = __uint_as_float(q.x << 16);
    f[1] = __uint_as_float(q.x & 0xFFFF0000u);
    f[2] = __uint_as_float(q.y << 16);
    f[3] = __uint_as_float(q.y & 0xFFFF0000u);
}

// 8 lanes per point, 4 channels per lane. Corner gather = one 64B segment.
__global__ __launch_bounds__(256) void fv_sample(const float* __restrict__ x,
                                                 const ushort* __restrict__ vol,
                                                 float* __restrict__ out,
                                                 int npts) {
    const int gid = blockIdx.x * 256 + threadIdx.x;
    const int p = gid >> 3;
    if (p >= npts) return;
    const int lane8 = gid & 7;       // uint2 slot within a 64B corner record

    const float cx = x[3 * p + 0];
    const float cy = x[3 * p + 1];
    const float cz = x[3 * p + 2];

    // match ref: clip((c+1)*0.5*(size-1), 0, size-1)
    const float fx = fminf(fmaxf((cx + 1.0f) * 0.5f * 128.0f, 0.0f), 128.0f);
    const float fy = fminf(fmaxf((cy + 1.0f) * 0.5f * 128.0f, 0.0f), 128.0f);
    const float fz = fminf(fmaxf((cz + 1.0f) * 0.5f * 128.0f, 0.0f), 128.0f);

    const float fx0 = floorf(fx), fy0 = floorf(fy), fz0 = floorf(fz);
    const int ix0 = (int)fx0, iy0 = (int)fy0, iz0 = (int)fz0;
    const float tx = fx - fx0, ty = fy - fy0, tz = fz - fz0;
    const uint32_t dX = (ix0 < GRIDW - 1) ? 8u : 0u;                  // uint2 units
    const uint32_t dY = (iy0 < GRIDW - 1) ? (GRIDW * 8u) : 0u;
    const uint32_t dZ = (iz0 < GRIDW - 1) ? (GRIDW * GRIDW * 8u) : 0u;

    // uint2-element offsets (8B units): s*8 + lane8; max 17.2M fits u32
    const uint32_t o000 = (uint32_t)((iz0 * GRIDW + iy0) * GRIDW + ix0) * 8u + (uint32_t)lane8;
    const uint32_t o001 = o000 + dX;
    const uint32_t o010 = o000 + dY;
    const uint32_t o011 = o010 + dX;
    const uint32_t o100 = o000 + dZ;
    const uint32_t o101 = o100 + dX;
    const uint32_t o110 = o100 + dY;
    const uint32_t o111 = o110 + dX;

    const uint2* __restrict__ vp = reinterpret_cast<const uint2*>(vol);
    const uint2 q000 = vp[o000];
    const uint2 q001 = vp[o001];
    const uint2 q010 = vp[o010];
    const uint2 q011 = vp[o011];
    const uint2 q100 = vp[o100];
    const uint2 q101 = vp[o101];
    const uint2 q110 = vp[o110];
    const uint2 q111 = vp[o111];

    const float wx1 = tx, wx0 = 1.0f - tx;
    const float wy1 = ty, wy0 = 1.0f - ty;
    const float wz1 = tz, wz0 = 1.0f - tz;
    const float wzy00 = wz0 * wy0, wzy01 = wz0 * wy1;
    const float wzy10 = wz1 * wy0, wzy11 = wz1 * wy1;
    const float w000 = wzy00 * wx0, w001 = wzy00 * wx1;
    const float w010 = wzy01 * wx0, w011 = wzy01 * wx1;
    const float w100 = wzy10 * wx0, w101 = wzy10 * wx1;
    const float w110 = wzy11 * wx0, w111 = wzy11 * wx1;

    float f[4], acc[4];
    bf16x4_to_f(q000, f);
#pragma unroll
    for (int j = 0; j < 4; ++j) acc[j] = w000 * f[j];
    bf16x4_to_f(q001, f);
#pragma unroll
    for (int j = 0; j < 4; ++j) acc[j] += w001 * f[j];
    bf16x4_to_f(q010, f);
#pragma unroll
    for (int j = 0; j < 4; ++j) acc[j] += w010 * f[j];
    bf16x4_to_f(q011, f);
#pragma unroll
    for (int j = 0; j < 4; ++j) acc[j] += w011 * f[j];
    bf16x4_to_f(q100, f);
#pragma unroll
    for (int j = 0; j < 4; ++j) acc[j] += w100 * f[j];
    bf16x4_to_f(q101, f);
#pragma unroll
    for (int j = 0; j < 4; ++j) acc[j] += w101 * f[j];
    bf16x4_to_f(q110, f);
#pragma unroll
    for (int j = 0; j < 4; ++j) acc[j] += w110 * f[j];
    bf16x4_to_f(q111, f);
#pragma unroll
    for (int j = 0; j < 4; ++j) acc[j] += w111 * f[j];

    // streamed output, never re-read: bypass cache so vol stays resident
    f32x4 r = {acc[0], acc[1], acc[2], acc[3]};
    f32x4* dst = reinterpret_cast<f32x4*>(out + (size_t)p * NCH) + lane8;
    __builtin_nontemporal_store(r, dst);
}

// Fallback (ws too small for bf16 volume): gather directly from fm [C][S] f32.
__global__ __launch_bounds__(256) void fv_sample_direct(const float* __restrict__ x,
                                                        const float* __restrict__ fm,
                                                        float* __restrict__ out,
                                                        int npts) {
    const int gid = blockIdx.x * 256 + threadIdx.x;
    const int p = gid >> 5;
    if (p >= npts) return;
    const int c = gid & 31;

    const float cx = x[3 * p + 0];
    const float cy = x[3 * p + 1];
    const float cz = x[3 * p + 2];

    const float fx = fminf(fmaxf((cx + 1.0f) * 0.5f * 128.0f, 0.0f), 128.0f);
    const float fy = fminf(fmaxf((cy + 1.0f) * 0.5f * 128.0f, 0.0f), 128.0f);
    const float fz = fminf(fmaxf((cz + 1.0f) * 0.5f * 128.0f, 0.0f), 128.0f);

    const float fx0 = floorf(fx), fy0 = floorf(fy), fz0 = floorf(fz);
    const int ix0 = (int)fx0, iy0 = (int)fy0, iz0 = (int)fz0;
    const float tx = fx - fx0, ty = fy - fy0, tz = fz - fz0;
    const int dX = (ix0 < GRIDW - 1) ? 1 : 0;
    const int dY = (iy0 < GRIDW - 1) ? GRIDW : 0;
    const int dZ = (iz0 < GRIDW - 1) ? (GRIDW * GRIDW) : 0;

    const int s000 = (iz0 * GRIDW + iy0) * GRIDW + ix0;
    const float* b = fm + (size_t)c * S_TOTAL;
    const float v000 = b[s000];
    const float v001 = b[s000 + dX];
    const float v010 = b[s000 + dY];
    const float v011 = b[s000 + dY + dX];
    const float v100 = b[s000 + dZ];
    const float v101 = b[s000 + dZ + dX];
    const float v110 = b[s000 + dZ + dY];
    const float v111 = b[s000 + dZ + dY + dX];

    const float wx1 = tx, wx0 = 1.0f - tx;
    const float wy1 = ty, wy0 = 1.0f - ty;
    const float wz1 = tz, wz0 = 1.0f - tz;

    const float r = v000 * (wz0 * wy0 * wx0) + v001 * (wz0 * wy0 * wx1) +
                    v010 * (wz0 * wy1 * wx0) + v011 * (wz0 * wy1 * wx1) +
                    v100 * (wz1 * wy0 * wx0) + v101 * (wz1 * wy0 * wx1) +
                    v110 * (wz1 * wy1 * wx0) + v111 * (wz1 * wy1 * wx1);

    out[(size_t)p * NCH + c] = r;
}

extern "C" void kernel_launch(void* const* d_in, const int* in_sizes, int n_in,
                              void* d_out, int out_size, void* d_ws, size_t ws_size,
                              hipStream_t stream) {
    const float* x = (const float*)d_in[0];
    const float* fm = (const float*)d_in[1];
    float* out = (float*)d_out;
    const int npts = in_sizes[0] / 3;

    const size_t need = (size_t)S_TOTAL * NCH * sizeof(ushort);  // ~137.4 MB
    if (ws_size >= need) {
        const int tb = (S_TOTAL + 255) / 256;  // 8386
        fv_transpose<<<tb, 256, 0, stream>>>(fm, (ushort*)d_ws);
        const int nthreads = npts * 8;  // 8 lanes per point
        fv_sample<<<(nthreads + 255) / 256, 256, 0, stream>>>(
            x, (const ushort*)d_ws, out, npts);
    } else {
        const int nthreads = npts * 32;
        fv_sample_direct<<<(nthreads + 255) / 256, 256, 0, stream>>>(x, fm, out, npts);
    }
}